// Round 1
// baseline (849.428 us; speedup 1.0000x reference)
//
#include <hip/hip_runtime.h>
#include <math.h>

#define BATCH 64
#define NV    50000
#define NM    (NV*3)   // 150000 rows

__constant__ int c_par[23] = {0,0,0,1,2,3,4,5,6,7,8,9,9,9,12,13,14,16,17,18,19,20,21};

__global__ void zero_kernel(float* p, int n) {
    int i = blockIdx.x * blockDim.x + threadIdx.x;
    if (i < n) p[i] = 0.f;
}

// C[row][b] (MODE0) = A[row][:K] . Bm[b][:K] + add[row]          (v_shaped)
// C[b][row] (MODE1) = A[row][:K] . Bm[b][:K] + add[row][b]        (v_posed, transposed out)
template<int K, int MODE>
__global__ __launch_bounds__(256)
void gemm_kernel(const float* __restrict__ A, const float* __restrict__ Bm,
                 const float* __restrict__ add, float* __restrict__ C)
{
    __shared__ float As[32 * 256];   // [k][row]
    __shared__ float Bs[32 * 64];    // [k][b]
    const int tid   = threadIdx.x;
    const int brow0 = blockIdx.x * 256;
    const int ty = tid >> 3;         // 0..31
    const int tx = tid & 7;          // 0..7

    float acc[8][8];
    #pragma unroll
    for (int i = 0; i < 8; ++i)
        #pragma unroll
        for (int j = 0; j < 8; ++j) acc[i][j] = 0.f;

    const int arow = brow0 + tid;    // loader: one row per thread, 32 consecutive k
    const int bb   = tid & 63;       // loader for B
    const int kseg = tid >> 6;       // 0..3
    const int nch  = (K + 31) >> 5;

    for (int c = 0; c < nch; ++c) {
        const int k0 = c << 5;
        // ---- stage A tile ----
        if (arow < NM) {
            if ((K % 4 == 0) && (k0 + 32 <= K)) {
                const float4* src = (const float4*)(A + (size_t)arow * K + k0);
                #pragma unroll
                for (int q = 0; q < 8; ++q) {
                    float4 va = src[q];
                    As[(q*4+0)*256 + tid] = va.x;
                    As[(q*4+1)*256 + tid] = va.y;
                    As[(q*4+2)*256 + tid] = va.z;
                    As[(q*4+3)*256 + tid] = va.w;
                }
            } else {
                #pragma unroll
                for (int kk = 0; kk < 32; ++kk) {
                    float v = (k0 + kk < K) ? A[(size_t)arow * K + k0 + kk] : 0.f;
                    As[kk*256 + tid] = v;
                }
            }
        } else {
            #pragma unroll
            for (int kk = 0; kk < 32; ++kk) As[kk*256 + tid] = 0.f;
        }
        // ---- stage B tile ----
        if ((K % 4 == 0) && (k0 + 32 <= K)) {
            const float4* src = (const float4*)(Bm + (size_t)bb * K + k0 + kseg*8);
            float4 v0 = src[0], v1 = src[1];
            const int kb = kseg * 8;
            Bs[(kb+0)*64 + bb] = v0.x; Bs[(kb+1)*64 + bb] = v0.y;
            Bs[(kb+2)*64 + bb] = v0.z; Bs[(kb+3)*64 + bb] = v0.w;
            Bs[(kb+4)*64 + bb] = v1.x; Bs[(kb+5)*64 + bb] = v1.y;
            Bs[(kb+6)*64 + bb] = v1.z; Bs[(kb+7)*64 + bb] = v1.w;
        } else {
            #pragma unroll
            for (int q = 0; q < 8; ++q) {
                int kk = kseg * 8 + q;
                Bs[kk*64 + bb] = (k0 + kk < K) ? Bm[(size_t)bb * K + k0 + kk] : 0.f;
            }
        }
        __syncthreads();
        // ---- compute: 8x8 register tile, contiguous-lane LDS reads ----
        #pragma unroll 8
        for (int kk = 0; kk < 32; ++kk) {
            float4 a0 = *(const float4*)(As + kk*256 + ty*4);
            float4 a1 = *(const float4*)(As + kk*256 + 128 + ty*4);
            float4 b0 = *(const float4*)(Bs + kk*64 + tx*4);
            float4 b1 = *(const float4*)(Bs + kk*64 + 32 + tx*4);
            float av[8] = {a0.x,a0.y,a0.z,a0.w,a1.x,a1.y,a1.z,a1.w};
            float bv[8] = {b0.x,b0.y,b0.z,b0.w,b1.x,b1.y,b1.z,b1.w};
            #pragma unroll
            for (int i = 0; i < 8; ++i)
                #pragma unroll
                for (int j = 0; j < 8; ++j)
                    acc[i][j] += av[i] * bv[j];
        }
        __syncthreads();
    }

    if constexpr (MODE == 0) {
        // C[row][64b] = acc + v_template[row]
        #pragma unroll
        for (int i = 0; i < 8; ++i) {
            int row = brow0 + ((i < 4) ? (ty*4 + i) : (128 + ty*4 + (i-4)));
            if (row < NM) {
                float t = add[row];
                float4 r0 = {acc[i][0]+t, acc[i][1]+t, acc[i][2]+t, acc[i][3]+t};
                float4 r1 = {acc[i][4]+t, acc[i][5]+t, acc[i][6]+t, acc[i][7]+t};
                *(float4*)(C + (size_t)row*64 + tx*4)      = r0;
                *(float4*)(C + (size_t)row*64 + 32 + tx*4) = r1;
            }
        }
    } else {
        // C[b][row] = acc + vs[row][b]   (row-quads contiguous per b)
        #pragma unroll
        for (int h = 0; h < 2; ++h) {
            int row0 = brow0 + h*128 + ty*4;
            if (row0 < NM) {
                #pragma unroll
                for (int jj = 0; jj < 8; ++jj) {
                    int b = (jj < 4) ? (tx*4 + jj) : (32 + tx*4 + (jj-4));
                    float4 r;
                    r.x = acc[h*4+0][jj] + add[(size_t)(row0+0)*64 + b];
                    r.y = acc[h*4+1][jj] + add[(size_t)(row0+1)*64 + b];
                    r.z = acc[h*4+2][jj] + add[(size_t)(row0+2)*64 + b];
                    r.w = acc[h*4+3][jj] + add[(size_t)(row0+3)*64 + b];
                    *(float4*)(C + (size_t)b*NM + row0) = r;
                }
            }
        }
    }
}

// J[b][j][d] += sum_v Jr[j][v] * vs[v*3+d][b]
__global__ __launch_bounds__(256)
void jreduce_kernel(const float* __restrict__ vs, const float* __restrict__ Jr,
                    float* J)
{
    const int tid = threadIdx.x;
    const int b = tid & 63;
    const int g = tid >> 6;            // j range g*6 .. g*6+5
    float acc[6][3];
    #pragma unroll
    for (int jj = 0; jj < 6; ++jj) { acc[jj][0]=0.f; acc[jj][1]=0.f; acc[jj][2]=0.f; }
    const int v0 = blockIdx.x * 250;
    const int v1 = v0 + 250;           // 200 blocks * 250 = 50000 exactly
    for (int v = v0; v < v1; ++v) {
        float p0 = vs[(size_t)(v*3+0)*64 + b];
        float p1 = vs[(size_t)(v*3+1)*64 + b];
        float p2 = vs[(size_t)(v*3+2)*64 + b];
        #pragma unroll
        for (int jj = 0; jj < 6; ++jj) {
            float r = Jr[(size_t)(g*6+jj)*NV + v];
            acc[jj][0] += r*p0; acc[jj][1] += r*p1; acc[jj][2] += r*p2;
        }
    }
    #pragma unroll
    for (int jj = 0; jj < 6; ++jj)
        #pragma unroll
        for (int d = 0; d < 3; ++d)
            atomicAdd(&J[(size_t)(b*24 + g*6 + jj)*3 + d], acc[jj][d]);
}

// per-(b,j): rodrigues -> R, lrotmin; chain -> G; correction -> G' [b][24][12]
__global__ __launch_bounds__(192)
void pose_kernel(const float* __restrict__ pose, const float* __restrict__ J,
                 float* __restrict__ G, float* __restrict__ lrot)
{
    __shared__ float Gl[8][24][12];
    __shared__ float Gc[8][24][12];
    const int t  = threadIdx.x;            // 0..191
    const int bl = t / 24;                 // 0..7
    const int j  = t % 24;
    const int b  = blockIdx.x * 8 + bl;

    // rodrigues (replicates reference: norm(theta + 1e-8), normalize by that, renorm quat)
    float tx = pose[b*72 + j*3 + 0];
    float ty = pose[b*72 + j*3 + 1];
    float tz = pose[b*72 + j*3 + 2];
    float ax = tx + 1e-8f, ay = ty + 1e-8f, az = tz + 1e-8f;
    float angle = sqrtf(ax*ax + ay*ay + az*az);
    float nx = tx / angle, ny = ty / angle, nz = tz / angle;
    float half = 0.5f * angle;
    float sw = sinf(half);
    float qw = cosf(half), qx = sw*nx, qy = sw*ny, qz = sw*nz;
    float qn = sqrtf(qw*qw + qx*qx + qy*qy + qz*qz);
    qw /= qn; qx /= qn; qy /= qn; qz /= qn;
    float w2=qw*qw, x2=qx*qx, y2=qy*qy, z2=qz*qz;
    float xy=qx*qy, xz=qx*qz, yz=qy*qz, wx=qw*qx, wy=qw*qy, wz=qw*qz;
    float r00 = w2+x2-y2-z2, r01 = 2.f*(xy-wz), r02 = 2.f*(wy+xz);
    float r10 = 2.f*(wz+xy), r11 = w2-x2+y2-z2, r12 = 2.f*(yz-wx);
    float r20 = 2.f*(xz-wy), r21 = 2.f*(wx+yz), r22 = w2-x2-y2+z2;

    if (j >= 1) {
        float* lr = lrot + (size_t)b*207 + (j-1)*9;
        lr[0]=r00-1.f; lr[1]=r01; lr[2]=r02;
        lr[3]=r10; lr[4]=r11-1.f; lr[5]=r12;
        lr[6]=r20; lr[7]=r21; lr[8]=r22-1.f;
    }
    float jx = J[(size_t)(b*24+j)*3+0];
    float jy = J[(size_t)(b*24+j)*3+1];
    float jz = J[(size_t)(b*24+j)*3+2];
    float rx = jx, ry = jy, rz = jz;       // rel translation
    if (j > 0) {
        int p = c_par[j-1];
        rx -= J[(size_t)(b*24+p)*3+0];
        ry -= J[(size_t)(b*24+p)*3+1];
        rz -= J[(size_t)(b*24+p)*3+2];
    }
    float* gl = Gl[bl][j];
    gl[0]=r00; gl[1]=r01; gl[2]=r02;  gl[3]=rx;
    gl[4]=r10; gl[5]=r11; gl[6]=r12;  gl[7]=ry;
    gl[8]=r20; gl[9]=r21; gl[10]=r22; gl[11]=rz;
    __syncthreads();

    if (j == 0) {   // serial kinematic chain per batch
        #pragma unroll
        for (int c = 0; c < 12; ++c) Gc[bl][0][c] = Gl[bl][0][c];
        for (int i = 1; i < 24; ++i) {
            int p = c_par[i-1];
            float* Aa = Gc[bl][p];
            float* Bb = Gl[bl][i];
            float* D  = Gc[bl][i];
            #pragma unroll
            for (int r = 0; r < 3; ++r) {
                float a0 = Aa[r*4+0], a1 = Aa[r*4+1], a2 = Aa[r*4+2], a3 = Aa[r*4+3];
                D[r*4+0] = a0*Bb[0] + a1*Bb[4] + a2*Bb[8];
                D[r*4+1] = a0*Bb[1] + a1*Bb[5] + a2*Bb[9];
                D[r*4+2] = a0*Bb[2] + a1*Bb[6] + a2*Bb[10];
                D[r*4+3] = a0*Bb[3] + a1*Bb[7] + a2*Bb[11] + a3;
            }
        }
    }
    __syncthreads();

    // correction: t' = t - R * J_rest(j); write G'[b][j][12]
    float* Gi = Gc[bl][j];
    float* go = G + (size_t)(b*24 + j) * 12;
    #pragma unroll
    for (int r = 0; r < 3; ++r) {
        go[r*4+0] = Gi[r*4+0];
        go[r*4+1] = Gi[r*4+1];
        go[r*4+2] = Gi[r*4+2];
        go[r*4+3] = Gi[r*4+3] - (Gi[r*4+0]*jx + Gi[r*4+1]*jy + Gi[r*4+2]*jz);
    }
}

// out[b][v][d] = sum_j w[v][j] * (G'[b][j] applied to vp[b][v])
__global__ __launch_bounds__(256)
void skin_kernel(const float* __restrict__ vp, const float* __restrict__ G,
                 const float* __restrict__ wts, float* __restrict__ out)
{
    const int v = blockIdx.x * 256 + threadIdx.x;
    if (v >= NV) return;
    const int b0 = blockIdx.y * 16;
    float w[24];
    const float4* wp = (const float4*)(wts + (size_t)v * 24);
    #pragma unroll
    for (int q = 0; q < 6; ++q) {
        float4 t = wp[q];
        w[q*4+0]=t.x; w[q*4+1]=t.y; w[q*4+2]=t.z; w[q*4+3]=t.w;
    }
    for (int b = b0; b < b0 + 16; ++b) {
        const float* pb = vp + (size_t)b * NM + v*3;
        float px = pb[0], py = pb[1], pz = pb[2];
        float ox = 0.f, oy = 0.f, oz = 0.f;
        const float* Gb = G + (size_t)b * 24 * 12;
        #pragma unroll
        for (int j = 0; j < 24; ++j) {
            const float* g = Gb + j*12;   // wave-uniform -> scalar loads
            float wj = w[j];
            ox += wj * (g[0]*px + g[1]*py + g[2]*pz  + g[3]);
            oy += wj * (g[4]*px + g[5]*py + g[6]*pz  + g[7]);
            oz += wj * (g[8]*px + g[9]*py + g[10]*pz + g[11]);
        }
        float* ob = out + (size_t)b * NM + v*3;
        ob[0] = ox; ob[1] = oy; ob[2] = oz;
    }
}

extern "C" void kernel_launch(void* const* d_in, const int* in_sizes, int n_in,
                              void* d_out, int out_size, void* d_ws, size_t ws_size,
                              hipStream_t stream) {
    const float* pose       = (const float*)d_in[0];
    const float* beta       = (const float*)d_in[1];
    const float* v_template = (const float*)d_in[2];
    const float* shapedirs  = (const float*)d_in[3];
    const float* posedirs   = (const float*)d_in[4];
    const float* Jreg       = (const float*)d_in[5];
    const float* weights    = (const float*)d_in[6];
    float* out = (float*)d_out;

    char* ws = (char*)d_ws;
    float* vs_ws   = (float*)(ws);                          // [NM][64]  38.4 MB
    float* vp_ws   = (float*)(ws + 38400000);               // [64][NM]  38.4 MB
    float* J_ws    = (float*)(ws + 76800000);               // [64][24][3]
    float* G_ws    = (float*)(ws + 76818432);               // [64][24][12]
    float* lrot_ws = (float*)(ws + 76892160);               // [64][207]

    zero_kernel<<<18, 256, 0, stream>>>(J_ws, 64*24*3);
    gemm_kernel<300, 0><<<586, 256, 0, stream>>>(shapedirs, beta, v_template, vs_ws);
    jreduce_kernel<<<200, 256, 0, stream>>>(vs_ws, Jreg, J_ws);
    pose_kernel<<<8, 192, 0, stream>>>(pose, J_ws, G_ws, lrot_ws);
    gemm_kernel<207, 1><<<586, 256, 0, stream>>>(posedirs, lrot_ws, vs_ws, vp_ws);
    skin_kernel<<<dim3(196, 4), 256, 0, stream>>>(vp_ws, G_ws, weights, out);
}

// Round 2
// 702.601 us; speedup vs baseline: 1.2090x; 1.2090x over previous
//
#include <hip/hip_runtime.h>
#include <math.h>

#define NV 50000
#define NM 150000   // 50000*3 rows

// par[j] for j in 0..23 (par[0] unused); depth[j] = chain depth
__constant__ int c_par[24]   = {0, 0,0,0, 1,2,3, 4,5,6, 7,8,9,9,9, 12,13,14, 16,17, 18,19, 20,21};
__constant__ int c_depth[24] = {0, 1,1,1, 2,2,2, 3,3,3, 4,4,4,4,4, 5,5,5, 6,6, 7,7, 8,8};

// transpose beta [64][300] -> betaT [300][64]; zero J [64][24][3]
__global__ __launch_bounds__(256)
void prep_kernel(const float* __restrict__ beta, float* __restrict__ betaT,
                 float* __restrict__ J)
{
    int i = blockIdx.x * 256 + threadIdx.x;
    if (i < 300 * 64) {
        int k = i >> 6, b = i & 63;
        betaT[i] = beta[b * 300 + k];
    }
    if (i < 64 * 24 * 3) J[i] = 0.f;
}

// Batch-in-registers GEMM: C[row][b] = A[row][:K] . Bt[:K][b]
// thread = one row, half the batch (acc[32]); B values are wave-uniform -> s_load.
// MODE0: C[row*64+b] = acc + add[row]            (v_shaped,  [NM][64])
// MODE1: C[b*NM+row] = acc + add[row*64+b]       (v_posed,   [64][NM])
template<int K, int MODE>
__global__ __launch_bounds__(128)
void gemm_kernel(const float* __restrict__ A, const float* __restrict__ Bt,
                 const float* __restrict__ add, float* __restrict__ C)
{
    __shared__ float As[64 * 33];          // 64 rows x 32 k, pitch 33 (conflict-free)
    const int t    = threadIdx.x;
    const int row0 = blockIdx.x * 64;
    const int lrow = t & 63;
    const int half = __builtin_amdgcn_readfirstlane(t >> 6);   // wave-uniform 0/1
    const int row  = row0 + lrow;

    float acc[32];
    #pragma unroll
    for (int b = 0; b < 32; ++b) acc[b] = 0.f;

    const int srow = t >> 3;   // 0..15 (staging row within pass)
    const int skg  = t & 7;    // 0..7  (k-group: float4)

    const int nfull = K / 32;
    for (int c = 0; c < nfull; ++c) {
        const int k0 = c * 32;
        __syncthreads();
        // coalesced staging: 8 lanes x 16B = 128B contiguous per row
        #pragma unroll
        for (int p = 0; p < 4; ++p) {
            int r = p * 16 + srow;
            float4 v = make_float4(0.f, 0.f, 0.f, 0.f);
            if (row0 + r < NM)
                v = *(const float4*)(A + (size_t)(row0 + r) * K + k0 + skg * 4);
            float* d = As + r * 33 + skg * 4;
            d[0] = v.x; d[1] = v.y; d[2] = v.z; d[3] = v.w;
        }
        __syncthreads();
        #pragma unroll 4
        for (int k = 0; k < 32; ++k) {
            float a = As[lrow * 33 + k];
            const float* Bk = Bt + (size_t)(k0 + k) * 64 + half * 32;  // uniform -> SGPR
            #pragma unroll
            for (int b = 0; b < 32; ++b) acc[b] = fmaf(Bk[b], a, acc[b]);
        }
    }
    // K tail (300 -> 12, 207 -> 15)
    const int krem = K - nfull * 32;
    if (krem > 0) {
        const int k0 = nfull * 32;
        __syncthreads();
        #pragma unroll
        for (int p = 0; p < 4; ++p) {
            int r = p * 16 + srow;
            #pragma unroll
            for (int q = 0; q < 4; ++q) {
                int k = skg * 4 + q;
                float v = 0.f;
                if (k < krem && row0 + r < NM)
                    v = A[(size_t)(row0 + r) * K + k0 + k];
                As[r * 33 + k] = v;
            }
        }
        __syncthreads();
        for (int k = 0; k < krem; ++k) {
            float a = As[lrow * 33 + k];
            const float* Bk = Bt + (size_t)(k0 + k) * 64 + half * 32;
            #pragma unroll
            for (int b = 0; b < 32; ++b) acc[b] = fmaf(Bk[b], a, acc[b]);
        }
    }

    if (row >= NM) return;
    if constexpr (MODE == 0) {
        float t0 = add[row];
        float* dst = C + (size_t)row * 64 + half * 32;   // 128B line per thread
        #pragma unroll
        for (int q = 0; q < 8; ++q) {
            float4 v = {acc[q*4+0] + t0, acc[q*4+1] + t0, acc[q*4+2] + t0, acc[q*4+3] + t0};
            *(float4*)(dst + q * 4) = v;
        }
    } else {
        const float* av = add + (size_t)row * 64 + half * 32;
        #pragma unroll
        for (int b = 0; b < 32; ++b)   // lanes = consecutive rows -> coalesced stores
            C[(size_t)(half * 32 + b) * NM + row] = acc[b] + av[b];
    }
}

// J[b][j][d] += sum_v Jr[j][v] * vs[v*3+d][b]   (vs is [NM][64])
__global__ __launch_bounds__(256)
void jreduce_kernel(const float* __restrict__ vs, const float* __restrict__ Jr,
                    float* J)
{
    const int tid = threadIdx.x;
    const int b = tid & 63;
    const int g = __builtin_amdgcn_readfirstlane(tid >> 6);   // j group g*6..g*6+5
    float acc[6][3];
    #pragma unroll
    for (int jj = 0; jj < 6; ++jj) { acc[jj][0]=0.f; acc[jj][1]=0.f; acc[jj][2]=0.f; }
    const int v0 = blockIdx.x * 250;
    for (int v = v0; v < v0 + 250; ++v) {
        float p0 = vs[(size_t)(v*3+0)*64 + b];
        float p1 = vs[(size_t)(v*3+1)*64 + b];
        float p2 = vs[(size_t)(v*3+2)*64 + b];
        #pragma unroll
        for (int jj = 0; jj < 6; ++jj) {
            float r = Jr[(size_t)(g*6+jj)*NV + v];    // uniform -> s_load
            acc[jj][0] += r*p0; acc[jj][1] += r*p1; acc[jj][2] += r*p2;
        }
    }
    #pragma unroll
    for (int jj = 0; jj < 6; ++jj)
        #pragma unroll
        for (int d = 0; d < 3; ++d)
            atomicAdd(&J[(size_t)(b*24 + g*6 + jj)*3 + d], acc[jj][d]);
}

// per-(b,j): rodrigues -> R; lrotT [207][64]; level-parallel kinematic chain; G' [64][24][12]
__global__ __launch_bounds__(192)
void pose_kernel(const float* __restrict__ pose, const float* __restrict__ J,
                 float* __restrict__ G, float* __restrict__ lrotT)
{
    __shared__ float Gl[8][24][12];
    __shared__ float Gc[8][24][12];
    const int t  = threadIdx.x;
    const int bl = t / 24;
    const int j  = t % 24;
    const int b  = blockIdx.x * 8 + bl;

    float tx = pose[b*72 + j*3 + 0];
    float ty = pose[b*72 + j*3 + 1];
    float tz = pose[b*72 + j*3 + 2];
    float ax = tx + 1e-8f, ay = ty + 1e-8f, az = tz + 1e-8f;
    float angle = sqrtf(ax*ax + ay*ay + az*az);
    float nx = tx / angle, ny = ty / angle, nz = tz / angle;
    float half = 0.5f * angle;
    float sw = sinf(half);
    float qw = cosf(half), qx = sw*nx, qy = sw*ny, qz = sw*nz;
    float qn = sqrtf(qw*qw + qx*qx + qy*qy + qz*qz);
    qw /= qn; qx /= qn; qy /= qn; qz /= qn;
    float w2=qw*qw, x2=qx*qx, y2=qy*qy, z2=qz*qz;
    float xy=qx*qy, xz=qx*qz, yz=qy*qz, wx=qw*qx, wy=qw*qy, wz=qw*qz;
    float r00 = w2+x2-y2-z2, r01 = 2.f*(xy-wz), r02 = 2.f*(wy+xz);
    float r10 = 2.f*(wz+xy), r11 = w2-x2+y2-z2, r12 = 2.f*(yz-wx);
    float r20 = 2.f*(xz-wy), r21 = 2.f*(wx+yz), r22 = w2-x2-y2+z2;

    if (j >= 1) {   // lrotT[k][b], k = (j-1)*9 + c
        const int k9 = (j-1)*9;
        lrotT[(size_t)(k9+0)*64+b]=r00-1.f; lrotT[(size_t)(k9+1)*64+b]=r01;
        lrotT[(size_t)(k9+2)*64+b]=r02;     lrotT[(size_t)(k9+3)*64+b]=r10;
        lrotT[(size_t)(k9+4)*64+b]=r11-1.f; lrotT[(size_t)(k9+5)*64+b]=r12;
        lrotT[(size_t)(k9+6)*64+b]=r20;     lrotT[(size_t)(k9+7)*64+b]=r21;
        lrotT[(size_t)(k9+8)*64+b]=r22-1.f;
    }
    float jx = J[(size_t)(b*24+j)*3+0];
    float jy = J[(size_t)(b*24+j)*3+1];
    float jz = J[(size_t)(b*24+j)*3+2];
    float rx = jx, ry = jy, rz = jz;
    if (j > 0) {
        int p = c_par[j];
        rx -= J[(size_t)(b*24+p)*3+0];
        ry -= J[(size_t)(b*24+p)*3+1];
        rz -= J[(size_t)(b*24+p)*3+2];
    }
    float* gl = Gl[bl][j];
    gl[0]=r00; gl[1]=r01; gl[2]=r02;  gl[3]=rx;
    gl[4]=r10; gl[5]=r11; gl[6]=r12;  gl[7]=ry;
    gl[8]=r20; gl[9]=r21; gl[10]=r22; gl[11]=rz;
    __syncthreads();

    if (j == 0) {
        #pragma unroll
        for (int c = 0; c < 12; ++c) Gc[bl][0][c] = Gl[bl][0][c];
    }
    const int dj = c_depth[j];
    for (int lvl = 1; lvl <= 8; ++lvl) {
        __syncthreads();
        if (dj == lvl) {
            const float* Aa = Gc[bl][c_par[j]];
            const float* Bb = Gl[bl][j];
            float* D = Gc[bl][j];
            #pragma unroll
            for (int r = 0; r < 3; ++r) {
                float a0=Aa[r*4+0], a1=Aa[r*4+1], a2=Aa[r*4+2], a3=Aa[r*4+3];
                D[r*4+0] = a0*Bb[0] + a1*Bb[4] + a2*Bb[8];
                D[r*4+1] = a0*Bb[1] + a1*Bb[5] + a2*Bb[9];
                D[r*4+2] = a0*Bb[2] + a1*Bb[6] + a2*Bb[10];
                D[r*4+3] = a0*Bb[3] + a1*Bb[7] + a2*Bb[11] + a3;
            }
        }
    }
    __syncthreads();

    const float* Gi = Gc[bl][j];
    float* go = G + (size_t)(b*24 + j) * 12;
    #pragma unroll
    for (int r = 0; r < 3; ++r) {
        go[r*4+0] = Gi[r*4+0];
        go[r*4+1] = Gi[r*4+1];
        go[r*4+2] = Gi[r*4+2];
        go[r*4+3] = Gi[r*4+3] - (Gi[r*4+0]*jx + Gi[r*4+1]*jy + Gi[r*4+2]*jz);
    }
}

// out[b][v][d] = sum_j w[v][j] * (G'[b][j] applied to vp[b][v])
__global__ __launch_bounds__(256)
void skin_kernel(const float* __restrict__ vp, const float* __restrict__ G,
                 const float* __restrict__ wts, float* __restrict__ out)
{
    const int v = blockIdx.x * 256 + threadIdx.x;
    if (v >= NV) return;
    const int b0 = blockIdx.y * 8;
    float w[24];
    const float4* wp = (const float4*)(wts + (size_t)v * 24);
    #pragma unroll
    for (int q = 0; q < 6; ++q) {
        float4 t = wp[q];
        w[q*4+0]=t.x; w[q*4+1]=t.y; w[q*4+2]=t.z; w[q*4+3]=t.w;
    }
    for (int b = b0; b < b0 + 8; ++b) {
        const float* pb = vp + (size_t)b * NM + v*3;
        float px = pb[0], py = pb[1], pz = pb[2];
        float ox = 0.f, oy = 0.f, oz = 0.f;
        const float* Gb = G + (size_t)b * 24 * 12;
        #pragma unroll
        for (int j = 0; j < 24; ++j) {
            const float* g = Gb + j*12;   // uniform -> s_load
            float wj = w[j];
            ox += wj * (g[0]*px + g[1]*py + g[2]*pz  + g[3]);
            oy += wj * (g[4]*px + g[5]*py + g[6]*pz  + g[7]);
            oz += wj * (g[8]*px + g[9]*py + g[10]*pz + g[11]);
        }
        float* ob = out + (size_t)b * NM + v*3;
        ob[0] = ox; ob[1] = oy; ob[2] = oz;
    }
}

extern "C" void kernel_launch(void* const* d_in, const int* in_sizes, int n_in,
                              void* d_out, int out_size, void* d_ws, size_t ws_size,
                              hipStream_t stream) {
    const float* pose       = (const float*)d_in[0];
    const float* beta       = (const float*)d_in[1];
    const float* v_template = (const float*)d_in[2];
    const float* shapedirs  = (const float*)d_in[3];
    const float* posedirs   = (const float*)d_in[4];
    const float* Jreg       = (const float*)d_in[5];
    const float* weights    = (const float*)d_in[6];
    float* out = (float*)d_out;

    char* ws = (char*)d_ws;
    float* vs_ws    = (float*)(ws);                 // [NM][64]  38.4 MB
    float* vp_ws    = (float*)(ws + 38400000);      // [64][NM]  38.4 MB
    float* betaT_ws = (float*)(ws + 38400000);      // [300][64] aliases vp (dead before gemm2)
    float* J_ws     = (float*)(ws + 76800000);      // [64][24][3]
    float* G_ws     = (float*)(ws + 76818432);      // [64][24][12]
    float* lrotT_ws = (float*)(ws + 76892160);      // [207][64]

    prep_kernel<<<75, 256, 0, stream>>>(beta, betaT_ws, J_ws);
    gemm_kernel<300, 0><<<2344, 128, 0, stream>>>(shapedirs, betaT_ws, v_template, vs_ws);
    jreduce_kernel<<<200, 256, 0, stream>>>(vs_ws, Jreg, J_ws);
    pose_kernel<<<8, 192, 0, stream>>>(pose, J_ws, G_ws, lrotT_ws);
    gemm_kernel<207, 1><<<2344, 128, 0, stream>>>(posedirs, lrotT_ws, vs_ws, vp_ws);
    skin_kernel<<<dim3(196, 8), 256, 0, stream>>>(vp_ws, G_ws, weights, out);
}